// Round 1
// 378.127 us; speedup vs baseline: 1.0511x; 1.0511x over previous
//
#include <hip/hip_runtime.h>

// StatefulRecurrent: s_t = A*s_{t-1} + x_t (complex diagonal A), out = [Re(s),Im(s)].
// B=16, T=4096, D=512. Two-kernel chunked scan, each thread owns 2 consecutive d:
//   K1: per-(d-pair, 64-step segment) aggregate (zero-init local scan)  [reads x, float2/lane]
//   K2: incoming state via rescan of cache-resident aggregates (S = A^64*S + agg_j),
//       then replay segment writing out (float4/lane stores).
//
// This revision: cache-stream separation.
//   - K1 x loads NORMAL: they deliberately warm L3 (x=134MB < 256MB L3) so K2's re-read hits L3.
//   - K2 x loads NONTEMPORAL (last use), out stores NONTEMPORAL (zero reuse) -> the 268MB
//     write stream no longer evicts x from L3 or the 4MB agg buf from L2, so the rescan
//     (132MB logical) and the x re-read stay cache-hits instead of HBM fetches.
//   - Rescan unroll 4 -> 8 (more outstanding L2/L3 loads in the prologue).

#define B_  16
#define T_  4096
#define D_  512
#define SEG 64
#define NS  (T_ / SEG)     // 64 segments
#define BD  (B_ * D_)      // 8192 chains (float2 entries per segment in buf)

typedef float v2f __attribute__((ext_vector_type(2)));
typedef float v4f __attribute__((ext_vector_type(4)));

// Block mapping (1024 blocks x 256 threads):
//   n: sq = n & 15 (segment-quad), dt = (n>>4)&3 (d-tile of 128), b = n>>6
//   tid: lane = tid&63, g = tid>>6 -> seg = sq*4+g ; d = dt*128 + lane*2
// Wave = 64 lanes x 2 d = 128 consecutive d: x loads 512 B/wave, out stores 1 KB/wave.

__global__ __launch_bounds__(256) void seg_agg_kernel(
    const float* __restrict__ x,
    const float* __restrict__ Ar_g, const float* __restrict__ Ai_g,
    float2* __restrict__ buf) {
  int tid  = threadIdx.x;
  int lane = tid & 63;
  int g    = tid >> 6;
  int n    = blockIdx.x;
  int sq   = n & 15;
  int dt   = (n >> 4) & 3;
  int b    = n >> 6;
  int d    = dt * 128 + lane * 2;
  int seg  = sq * 4 + g;
  int t0   = seg * SEG;

  float2 Ar = *(const float2*)(Ar_g + d);
  float2 Ai = *(const float2*)(Ai_g + d);
  float s0r = 0.f, s0i = 0.f, s1r = 0.f, s1i = 0.f;
  // NORMAL (caching) loads on purpose: this pass populates L3 with x for apply_kernel.
  const float2* xp = (const float2*)(x + ((size_t)(b * T_ + t0)) * D_ + d);
#pragma unroll 8
  for (int k = 0; k < SEG; ++k) {
    float2 xv = xp[(size_t)k * (D_ / 2)];
    float n0r = fmaf(s0r, Ar.x, fmaf(-s0i, Ai.x, xv.x));
    float n0i = fmaf(s0r, Ai.x, s0i * Ar.x);
    float n1r = fmaf(s1r, Ar.y, fmaf(-s1i, Ai.y, xv.y));
    float n1i = fmaf(s1r, Ai.y, s1i * Ar.y);
    s0r = n0r; s0i = n0i; s1r = n1r; s1i = n1i;
  }
  float4 agg = make_float4(s0r, s0i, s1r, s1i);
  *(float4*)(buf + (size_t)seg * BD + b * D_ + d) = agg;   // cached: reused ~33x by K2
}

__global__ __launch_bounds__(256) void apply_kernel(
    const float* __restrict__ x,
    const float* __restrict__ Ar_g, const float* __restrict__ Ai_g,
    const float2* __restrict__ buf,
    float4* __restrict__ out4) {
  int tid  = threadIdx.x;
  int lane = tid & 63;
  int g    = tid >> 6;
  int n    = blockIdx.x;
  int sq   = n & 15;
  int dt   = (n >> 4) & 3;
  int b    = n >> 6;
  int d    = dt * 128 + lane * 2;
  int seg  = sq * 4 + g;
  int t0   = seg * SEG;

  float2 Ar = *(const float2*)(Ar_g + d);
  float2 Ai = *(const float2*)(Ai_g + d);

  // A^64 per d-component by 6 squarings
  float p0r = Ar.x, p0i = Ai.x, p1r = Ar.y, p1i = Ai.y;
#pragma unroll
  for (int q = 0; q < 6; ++q) {
    float t0r = p0r * p0r - p0i * p0i; float t0i = 2.f * p0r * p0i;
    float t1r = p1r * p1r - p1i * p1i; float t1i = 2.f * p1r * p1i;
    p0r = t0r; p0i = t0i; p1r = t1r; p1i = t1i;
  }

  // Incoming state: S = sum_{j<seg} A^{64(seg-1-j)} * agg_j, computed as S = A64*S + agg_j.
  // buf is 4 MB -> should be L2/L3 resident (the nt out-stream below no longer evicts it).
  // NORMAL loads (reuse). Unroll 8: more loads in flight against L2/L3 latency.
  float S0r = 0.f, S0i = 0.f, S1r = 0.f, S1i = 0.f;
  const float* bbase = (const float*)(buf + b * D_ + d);
#pragma unroll 8
  for (int j = 0; j < seg; ++j) {
    float4 gv = *(const float4*)(bbase + (size_t)j * (BD * 2));
    float n0r = fmaf(p0r, S0r, fmaf(-p0i, S0i, gv.x));
    float n0i = fmaf(p0i, S0r, fmaf(p0r, S0i, gv.y));
    float n1r = fmaf(p1r, S1r, fmaf(-p1i, S1i, gv.z));
    float n1i = fmaf(p1i, S1r, fmaf(p1r, S1i, gv.w));
    S0r = n0r; S0i = n0i; S1r = n1r; S1i = n1i;
  }

  // Replay segment from incoming state, writing float4 {s0r,s0i,s1r,s1i} per step.
  // x: nontemporal load (last use; it's L3-resident from K1, don't re-allocate).
  // out: nontemporal store (never read again; don't thrash L2/L3).
  const v2f* xp = (const v2f*)(x + ((size_t)(b * T_ + t0)) * D_ + d);
  v4f* op = (v4f*)(out4 + (((size_t)(b * T_ + t0)) * D_ + d) / 2);
#pragma unroll 8
  for (int k = 0; k < SEG; ++k) {
    v2f xv = __builtin_nontemporal_load(xp + (size_t)k * (D_ / 2));
    float n0r = fmaf(S0r, Ar.x, fmaf(-S0i, Ai.x, xv.x));
    float n0i = fmaf(S0r, Ai.x, S0i * Ar.x);
    float n1r = fmaf(S1r, Ar.y, fmaf(-S1i, Ai.y, xv.y));
    float n1i = fmaf(S1r, Ai.y, S1i * Ar.y);
    S0r = n0r; S0i = n0i; S1r = n1r; S1i = n1i;
    v4f ov = {S0r, S0i, S1r, S1i};
    __builtin_nontemporal_store(ov, op + (size_t)k * (D_ / 2));
  }
}

extern "C" void kernel_launch(void* const* d_in, const int* in_sizes, int n_in,
                              void* d_out, int out_size, void* d_ws, size_t ws_size,
                              hipStream_t stream) {
  const float* x  = (const float*)d_in[0];
  const float* Ar = (const float*)d_in[1];
  const float* Ai = (const float*)d_in[2];
  float4* out = (float4*)d_out;
  float2* buf = (float2*)d_ws;  // NS*BD float2 = 4 MB scratch

  seg_agg_kernel<<<dim3(1024), dim3(256), 0, stream>>>(x, Ar, Ai, buf);
  apply_kernel<<<dim3(1024), dim3(256), 0, stream>>>(x, Ar, Ai, buf, out);
}